// Round 1
// 20482.935 us; speedup vs baseline: 1.6828x; 1.6828x over previous
//
#include <hip/hip_runtime.h>
#include <hip/hip_bf16.h>
#include <hip/hip_fp16.h>
#include <math.h>

// ---------------------------------------------------------------------------
// Seq2Seq (bi-LSTM encoder x2 layers + fixed-state decoder), B=64 T=1024 H=256
// This round:
//  * h exchange via agent-scope RELAXED atomics (sc1: coherent-point ld/st)
//    -> per-step direction barrier is FENCE-FREE (no buffer_wbl2/buffer_inv).
//    Full fenced barrier kept for phase transitions (y0/finals are plain).
//  * per-direction step barriers (16 ctrs x 8 WGs) decouple fwd/bwd.
//  * E1: y0 kept fp16 in LDS, dotted with v_dot2_f32_f16 (fp32 accum);
//    one staging phase instead of two; Wih1 staged bf16->fp16 (exact).
//  * y0 register prefetch (next step) + hoisted x load in E0.
// ---------------------------------------------------------------------------

#define AST 132          // LDS row stride (floats) for fp32 A tiles
#define AST2 520         // LDS row stride (fp16) for fp16 A tile / W16
#define NWG 256
#define THR 512
#define HALF_F (64 * AST)   // 8448 floats per A half-buffer

// ws layout (float offsets); first 2048 floats = barrier counters (8 KB)
//   full barrier: ctrs[0..31]; dir barriers: ctrs[32 + dir*16 + g]
#define HBOF   2048                 // h double buffers: [dir*2+buf][b*256+k]
#define ECL0   (HBOF + 65536)       // enc l0 final c: [dir][b*256+k]
#define EHL1   (ECL0 + 32768)       // enc l1 final h
#define ECL1   (EHL1 + 32768)       // enc l1 final c
#define ROF    (ECL1 + 32768)       // decoder recurrent consts R: [m][b*1024+r]
#define ZBOF   (ROF + 262144)       // decoder z double buffer: [sel][b*512+j]
#define PYOF   (ZBOF + 65536)       // decoder partial y: [w*64+b]
#define Y0OF   524288               // fp16 y0: [t][b*512 + dir*256 + c]
#define WS_REQ_BYTES ((size_t)(Y0OF + 16777216) * 4)   // ~66 MB (unchanged)

struct SeqParams {
  const void *x, *eWih0, *eWhh0, *eB0, *eWih1, *eWhh1, *eB1;
  const void *dWih0, *dWhh0, *dB0, *dWih1, *dWhh1, *dB1, *fcW, *fcb;
  void* out;
  float* ws;
  unsigned* ctrs;
};

typedef _Float16 hlf2 __attribute__((ext_vector_type(2)));

__device__ __forceinline__ float bf2f(unsigned short u) {
  return __uint_as_float(((unsigned)u) << 16);
}
__device__ __forceinline__ float hf2f(unsigned short u) {
  __half_raw r; r.x = u; return __half2float(__half(r));
}
__device__ __forceinline__ unsigned short f2h_u(float f) {
  __half h = __float2half(f);
  return *reinterpret_cast<unsigned short*>(&h);
}
__device__ __forceinline__ float sigm(float v) { return 1.0f / (1.0f + expf(-v)); }

#if __has_builtin(__builtin_amdgcn_fdot2)
__device__ __forceinline__ float fdot2(hlf2 a, hlf2 b, float c) {
  return __builtin_amdgcn_fdot2(a, b, c, false);
}
#else
__device__ __forceinline__ float fdot2(hlf2 a, hlf2 b, float c) {
  return c + (float)a[0] * (float)b[0] + (float)a[1] * (float)b[1];
}
#endif

__device__ __forceinline__ float ldin(const void* p_, size_t i, int bf) {
  return bf ? bf2f(((const unsigned short*)p_)[i]) : ((const float*)p_)[i];
}
__device__ __forceinline__ void stout(void* o, size_t i, float v, int bf) {
  if (bf) ((__hip_bfloat16*)o)[i] = __float2bfloat16(v);
  else    ((float*)o)[i] = v;
}

// probe storage dtype from x (N(0,1) samples)
__device__ __forceinline__ int detect_bf16(const void* xp) {
  const unsigned* u = (const unsigned*)xp;
  int votes = 0;
#pragma unroll 8
  for (int i = 0; i < 64; ++i) {
    unsigned e = (u[i] >> 7) & 0xFF;
    votes += (e >= 108 && e <= 131) ? 1 : 0;
  }
  return votes >= 32;
}

// ---- coherent-point (sc1) exchange for recurrent h -------------------------
__device__ __forceinline__ void hstore(float* p2, float v) {
  __hip_atomic_store(p2, v, __ATOMIC_RELAXED, __HIP_MEMORY_SCOPE_AGENT);
}
__device__ __forceinline__ float4 hload4(const float* p2) {
  unsigned long long u0 = __hip_atomic_load((unsigned long long*)p2,
                                            __ATOMIC_RELAXED, __HIP_MEMORY_SCOPE_AGENT);
  unsigned long long u1 = __hip_atomic_load((unsigned long long*)p2 + 1,
                                            __ATOMIC_RELAXED, __HIP_MEMORY_SCOPE_AGENT);
  return make_float4(__uint_as_float((unsigned)u0), __uint_as_float((unsigned)(u0 >> 32)),
                     __uint_as_float((unsigned)u1), __uint_as_float((unsigned)(u1 >> 32)));
}

// ---- full barrier (fenced release/acquire; phase transitions) --------------
__device__ __forceinline__ void gbar(unsigned* ctrs, unsigned gen) {
  __syncthreads();
  if (threadIdx.x == 0) {
    __hip_atomic_fetch_add(&ctrs[(blockIdx.x & 31) * 32], 1u,
                           __ATOMIC_RELEASE, __HIP_MEMORY_SCOPE_AGENT);
  }
  if (threadIdx.x < 32) {
    while (__hip_atomic_load(&ctrs[threadIdx.x * 32], __ATOMIC_RELAXED,
                             __HIP_MEMORY_SCOPE_AGENT) < gen * 8u) {
      __builtin_amdgcn_s_sleep(1);
    }
    (void)__hip_atomic_load(&ctrs[threadIdx.x * 32], __ATOMIC_ACQUIRE,
                            __HIP_MEMORY_SCOPE_AGENT);
  }
  __syncthreads();
}

// ---- per-direction step barrier (fence-free; h moves via sc1 atomics) ------
// __syncthreads drains vmcnt(0): h stores complete at the coherent point
// before the arrival add is issued. Spin relaxed; compiler-only acquire
// fence stops hoisting of the subsequent sc1 data loads. No wbl2/inv.
__device__ __forceinline__ void gbarD(unsigned* ctrs, int dir, int wl, unsigned gen) {
  __syncthreads();
  if (threadIdx.x == 0) {
    __hip_atomic_fetch_add(&ctrs[(32 + dir * 16 + (wl >> 3)) * 32], 1u,
                           __ATOMIC_RELAXED, __HIP_MEMORY_SCOPE_AGENT);
  }
  if (threadIdx.x < 16) {
    while (__hip_atomic_load(&ctrs[(32 + dir * 16 + threadIdx.x) * 32], __ATOMIC_RELAXED,
                             __HIP_MEMORY_SCOPE_AGENT) < gen * 8u) {
      __builtin_amdgcn_s_sleep(1);
    }
  }
  __atomic_signal_fence(__ATOMIC_ACQUIRE);
  __syncthreads();
}

// stage 64 rows x 128 floats from fp32 ws source (plain cached loads)
__device__ __forceinline__ void stage_A_f(float* Adst, const float* src, int stride, int koff) {
  const int t = threadIdx.x;
#pragma unroll
  for (int i = 0; i < 4; ++i) {
    int idx = t + i * THR;
    int b = idx >> 5, kq = (idx & 31) << 2;
    float4 v = *reinterpret_cast<const float4*>(src + (size_t)b * stride + koff + kq);
    *reinterpret_cast<float4*>(Adst + b * AST + kq) = v;
  }
}

// stage 64 rows x 128 floats of recurrent h via sc1 atomic loads
__device__ __forceinline__ void stage_A_fa(float* Adst, const float* src, int stride, int koff) {
  const int t = threadIdx.x;
#pragma unroll
  for (int i = 0; i < 4; ++i) {
    int idx = t + i * THR;
    int b = idx >> 5, kq = (idx & 31) << 2;
    float4 v = hload4(src + (size_t)b * stride + koff + kq);
    *reinterpret_cast<float4*>(Adst + b * AST + kq) = v;
  }
}

// stage 64 rows x 128 floats from fp16 ws source (R phase)
__device__ __forceinline__ void stage_A_h(float* Adst, const unsigned short* src, int stride, int koff) {
  const int t = threadIdx.x;
#pragma unroll
  for (int i = 0; i < 4; ++i) {
    int idx = t + i * THR;
    int b = idx >> 5, kq = (idx & 31) << 2;
    ushort4 u = *reinterpret_cast<const ushort4*>(src + (size_t)b * stride + koff + kq);
    *reinterpret_cast<float4*>(Adst + b * AST + kq) =
        make_float4(hf2f(u.x), hf2f(u.y), hf2f(u.z), hf2f(u.w));
  }
}

// stage 8 weight rows x 128 floats from global (bf16 or fp32 storage), fp32 LDS
__device__ __forceinline__ void stage_W_half(float* Wl, const void* src, int stride,
                                             int colbase, int wmode, int koff, int bf) {
  const int t = threadIdx.x;
  if (t < 256) {
    int rr = t >> 5, kq = (t & 31) << 2;
    int grow = wmode ? (colbase + rr) : ((rr >> 1) * 256 + colbase + (rr & 1));
    size_t off = (size_t)grow * stride + koff + kq;
    float4 v;
    if (bf) {
      ushort4 u = *reinterpret_cast<const ushort4*>((const unsigned short*)src + off);
      v = make_float4(bf2f(u.x), bf2f(u.y), bf2f(u.z), bf2f(u.w));
    } else {
      v = *reinterpret_cast<const float4*>((const float*)src + off);
    }
    *reinterpret_cast<float4*>(Wl + rr * AST + kq) = v;
  }
}

// stage 8 weight rows x 512 cols as fp16 (for fdot2); gate-major rows for
// h-cols colbase,colbase+1 (rr=(q<<1)|cc). bf16->fp16 is exact at this scale.
__device__ __forceinline__ void stage_W16(unsigned short* Wd, const void* src, int stride,
                                          int colbase, int bf) {
  const int t = threadIdx.x;             // 256 threads x 16 fp16
  if (t < 256) {
    int rr = t >> 5, kk = (t & 31) << 4;
    int grow = (rr >> 1) * 256 + colbase + (rr & 1);
    size_t off = (size_t)grow * stride + kk;
    __half hv[16];
    if (bf) {
      const unsigned short* sp = (const unsigned short*)src + off;
#pragma unroll
      for (int e = 0; e < 16; ++e) hv[e] = __float2half(bf2f(sp[e]));
    } else {
      const float* sp = (const float*)src + off;
#pragma unroll
      for (int e = 0; e < 16; ++e) hv[e] = __float2half(sp[e]);
    }
    *reinterpret_cast<uint4*>(Wd + rr * AST2 + kk)     = *reinterpret_cast<uint4*>(&hv[0]);
    *reinterpret_cast<uint4*>(Wd + rr * AST2 + kk + 8) = *reinterpret_cast<uint4*>(&hv[8]);
  }
}

// fp32 dot: acc[i*2+j] += A[bt+16i][k] * W[rt*2+j][k]; kc = wave (uniform)
__device__ __forceinline__ void dot_half(float4* acc, const float* A, const float* Wl) {
  const int t = threadIdx.x;
  const int kc = t >> 6, tile = t & 63;
  const int bt = tile >> 2, rt = tile & 3;
#pragma unroll
  for (int d = 0; d < 4; ++d) {
    const int k = kc * 16 + d * 4;
    float4 wv[2], hv[4];
#pragma unroll
    for (int j = 0; j < 2; ++j) wv[j] = *reinterpret_cast<const float4*>(Wl + (rt * 2 + j) * AST + k);
#pragma unroll
    for (int i = 0; i < 4; ++i) hv[i] = *reinterpret_cast<const float4*>(A + (bt + 16 * i) * AST + k);
#pragma unroll
    for (int i = 0; i < 4; ++i) {
#pragma unroll
      for (int j = 0; j < 2; ++j) {
        float4& a = acc[i * 2 + j];
        a.x += hv[i].x * wv[j].x;
        a.y += hv[i].y * wv[j].y;
        a.z += hv[i].z * wv[j].z;
        a.w += hv[i].w * wv[j].w;
      }
    }
  }
}

__device__ __forceinline__ void dot2acc(float4& a, const uint4& hv, const uint4& wv) {
  const hlf2* hp = reinterpret_cast<const hlf2*>(&hv);
  const hlf2* wp = reinterpret_cast<const hlf2*>(&wv);
  a.x = fdot2(hp[0], wp[0], a.x);
  a.y = fdot2(hp[1], wp[1], a.y);
  a.z = fdot2(hp[2], wp[2], a.z);
  a.w = fdot2(hp[3], wp[3], a.w);
}

// fp16 dot over K=512 in one call (v_dot2_f32_f16, fp32 accumulate).
// Row stride AST2=520 fp16 -> rows advance 4 banks; 16 distinct A rows per
// instr tile 2-way (free); 8 W rows conflict-free.
__device__ __forceinline__ void dot2_full(float4* acc, const unsigned short* Ah,
                                          const unsigned short* W16) {
  const int t = threadIdx.x;
  const int kc = t >> 6, tile = t & 63;
  const int bt = tile >> 2, rt = tile & 3;
  const unsigned short* wp0 = W16 + (rt * 2 + 0) * AST2 + kc * 64;
  const unsigned short* wp1 = W16 + (rt * 2 + 1) * AST2 + kc * 64;
  const unsigned short* ap0 = Ah + (bt + 0)  * AST2 + kc * 64;
  const unsigned short* ap1 = Ah + (bt + 16) * AST2 + kc * 64;
  const unsigned short* ap2 = Ah + (bt + 32) * AST2 + kc * 64;
  const unsigned short* ap3 = Ah + (bt + 48) * AST2 + kc * 64;
#pragma unroll
  for (int d = 0; d < 8; ++d) {
    const int k = d * 8;
    uint4 w0 = *reinterpret_cast<const uint4*>(wp0 + k);
    uint4 w1 = *reinterpret_cast<const uint4*>(wp1 + k);
    uint4 h0 = *reinterpret_cast<const uint4*>(ap0 + k);
    uint4 h1 = *reinterpret_cast<const uint4*>(ap1 + k);
    uint4 h2 = *reinterpret_cast<const uint4*>(ap2 + k);
    uint4 h3 = *reinterpret_cast<const uint4*>(ap3 + k);
    dot2acc(acc[0], h0, w0); dot2acc(acc[1], h0, w1);
    dot2acc(acc[2], h1, w0); dot2acc(acc[3], h1, w1);
    dot2acc(acc[4], h2, w0); dot2acc(acc[5], h2, w1);
    dot2acc(acc[6], h3, w0); dot2acc(acc[7], h3, w1);
  }
}

// deterministic 8-partial reduction -> gates[r*64+b] (8x64)
__device__ __forceinline__ void reduce_acc(const float4* acc, float* part, float* outbuf) {
  const int t = threadIdx.x;
  const int kc = t >> 6, tile = t & 63;
#pragma unroll
  for (int e = 0; e < 8; ++e) {
    const float4 a = acc[e];
    part[e * 512 + kc * 64 + tile] = (a.x + a.y) + (a.z + a.w);
  }
  __syncthreads();
  {
    const int r = t >> 6, b = t & 63;
    const int tl = (b & 15) * 4 + (r >> 1);
    const float* pp = part + ((b >> 4) * 2 + (r & 1)) * 512 + tl;
    float v = ((pp[0] + pp[64]) + (pp[128] + pp[192])) +
              ((pp[256] + pp[320]) + (pp[384] + pp[448]));
    outbuf[r * 64 + b] = v;
  }
  __syncthreads();
}

// same reduction but writes R consts to global with bias added
__device__ __forceinline__ void reduce_R(const float4* acc, float* part, float* dst,
                                         const void* bsrc, int rowbase, int bf) {
  const int t = threadIdx.x;
  const int kc = t >> 6, tile = t & 63;
#pragma unroll
  for (int e = 0; e < 8; ++e) {
    const float4 a = acc[e];
    part[e * 512 + kc * 64 + tile] = (a.x + a.y) + (a.z + a.w);
  }
  __syncthreads();
  {
    const int r = t >> 6, b = t & 63;
    const int tl = (b & 15) * 4 + (r >> 1);
    const float* pp = part + ((b >> 4) * 2 + (r & 1)) * 512 + tl;
    float v = ((pp[0] + pp[64]) + (pp[128] + pp[192])) +
              ((pp[256] + pp[320]) + (pp[384] + pp[448]));
    dst[(size_t)b * 1024 + rowbase + r] = v + ldin(bsrc, rowbase + r, bf);
  }
  __syncthreads();
}

// decoder layer-0 cells: z[b][j] from scalar y (WG w owns 128 elements)
__device__ __forceinline__ void dec_z(const SeqParams& p, float* ws, int w, int bufsel,
                                      const float* yl, int bf) {
  const int t = threadIdx.x;
  if (t < 128) {
    int e = w * 128 + t;
    int b = e >> 9, j = e & 511;
    int dir = j >> 8, k = j & 255;
    float y = yl ? yl[b] : 0.f;
    const float* rp = ws + ROF + dir * 65536 + (size_t)b * 1024;
    float gi = y * ldin(p.dWih0, dir * 1024 +       k, bf) + rp[      k];
    float gf = y * ldin(p.dWih0, dir * 1024 + 256 + k, bf) + rp[256 + k];
    float gg = y * ldin(p.dWih0, dir * 1024 + 512 + k, bf) + rp[512 + k];
    float go = y * ldin(p.dWih0, dir * 1024 + 768 + k, bf) + rp[768 + k];
    float cold = ws[ECL0 + dir * 16384 + b * 256 + k];
    float cn = sigm(gf) * cold + sigm(gi) * tanhf(gg);
    float hz = sigm(go) * tanhf(cn);
    ws[ZBOF + bufsel * 32768 + b * 512 + j] = hz;
  }
}

__global__ void __launch_bounds__(THR, 1) seq2seq_kernel(SeqParams p) {
  __shared__ __align__(16) float Abuf[2 * HALF_F];  // 16896 f; fp16 view 64x520
  __shared__ __align__(16) float Wl[6 * 8 * AST];   // 6336 f
  __shared__ __align__(16) float part[8 * 512];     // 4096 f
  __shared__ float gates[8 * 64];
  __shared__ float cst[2 * 64];
  __shared__ float ph[2 * 64];
  __shared__ float cb8[8], cw8[8];
  __shared__ float ylds[64], yprev[64], yprev2[64];

  float* const A0 = Abuf;
  float* const A1 = Abuf + HALF_F;
  unsigned short* const Ah  = reinterpret_cast<unsigned short*>(Abuf);
  unsigned short* const W16 = reinterpret_cast<unsigned short*>(Wl + 2 * 1056);

  const int w = blockIdx.x;
  const int t = threadIdx.x;
  float* ws = p.ws;
  unsigned short* y0u = (unsigned short*)(ws + Y0OF);
  unsigned* ctrs = p.ctrs;
  unsigned genF = 0, genD = 0;
  const int bfm = detect_bf16(p.x);

  // ============================ init + E0 prep =============================
  {
    if (t < 128) {                       // zero h buffers [dir][buf0]
      int e = w * 128 + t;
      int dirz = e >> 14, r = e & 16383;
      ws[HBOF + (dirz * 2 + 0) * 16384 + r] = 0.f;
    }
    const int dir = w >> 7, wl = w & 127;
    const void* whh0 = bfm ? (const void*)((const unsigned short*)p.eWhh0 + (size_t)dir * 262144)
                           : (const void*)((const float*)p.eWhh0 + (size_t)dir * 262144);
    stage_W_half(Wl,        whh0, 256, 2 * wl, 0, 0,   bfm);
    stage_W_half(Wl + 1056, whh0, 256, 2 * wl, 0, 128, bfm);
    if (t < 8) {
      int q = t >> 1, cc = t & 1;
      int grow = q * 256 + 2 * wl + cc;
      cb8[t] = ldin(p.eB0,   dir * 1024 + grow, bfm);
      cw8[t] = ldin(p.eWih0, dir * 1024 + grow, bfm);
    }
    if (t < 128) cst[t] = 0.f;
  }
  gbar(ctrs, ++genF);                    // full (fenced): flushes zeros/weights

  // ============================ E0: 1024 steps =============================
  {
    const int dir = w >> 7, wl = w & 127;
    for (int st = 0; st < 1024; ++st) {
      const int tt = dir ? (1023 - st) : st;
      float xv = 0.f;                    // hoisted: issue x load early
      if (t < 128) xv = ldin(p.x, (size_t)(t & 63) * 1024 + tt, bfm);
      float4 acc[8];
#pragma unroll
      for (int e = 0; e < 8; ++e) acc[e] = make_float4(0.f, 0.f, 0.f, 0.f);
      const float* hsrc = ws + HBOF + (dir * 2 + (st & 1)) * 16384;
      stage_A_fa(A0, hsrc, 256, 0);
      stage_A_fa(A1, hsrc, 256, 128);
      __syncthreads();
      dot_half(acc, A0, Wl);
      dot_half(acc, A1, Wl + 1056);
      reduce_acc(acc, part, gates);
      if (t < 128) {
        const int b = t & 63, cc = t >> 6, c = 2 * wl + cc;
        float gi = gates[(0 + cc) * 64 + b] + cb8[0 + cc] + xv * cw8[0 + cc];
        float gf = gates[(2 + cc) * 64 + b] + cb8[2 + cc] + xv * cw8[2 + cc];
        float gg = gates[(4 + cc) * 64 + b] + cb8[4 + cc] + xv * cw8[4 + cc];
        float go = gates[(6 + cc) * 64 + b] + cb8[6 + cc] + xv * cw8[6 + cc];
        float cold = cst[cc * 64 + b];
        float cn = sigm(gf) * cold + sigm(gi) * tanhf(gg);
        float hn = sigm(go) * tanhf(cn);
        cst[cc * 64 + b] = cn;
        hstore(&ws[HBOF + (dir * 2 + ((st + 1) & 1)) * 16384 + b * 256 + c], hn);
        y0u[(size_t)tt * 32768 + b * 512 + dir * 256 + c] = f2h_u(hn);
        if (st == 1023) ws[ECL0 + dir * 16384 + b * 256 + c] = cn;
      }
      gbarD(ctrs, dir, wl, ++genD);
    }
  }

  // ============================ E1 prep ====================================
  {
    if (t < 128) {
      int e = w * 128 + t;
      int dirz = e >> 14, r = e & 16383;
      ws[HBOF + (dirz * 2 + 0) * 16384 + r] = 0.f;
    }
    const int dir = w >> 7, wl = w & 127;
    const void* whh1 = bfm ? (const void*)((const unsigned short*)p.eWhh1 + (size_t)dir * 262144)
                           : (const void*)((const float*)p.eWhh1 + (size_t)dir * 262144);
    const void* wih1 = bfm ? (const void*)((const unsigned short*)p.eWih1 + (size_t)dir * 524288)
                           : (const void*)((const float*)p.eWih1 + (size_t)dir * 524288);
    stage_W_half(Wl,        whh1, 256, 2 * wl, 0, 0,   bfm);
    stage_W_half(Wl + 1056, whh1, 256, 2 * wl, 0, 128, bfm);
    stage_W16(W16, wih1, 512, 2 * wl, bfm);          // fp16 Wih1, K=512
    if (t < 8) {
      int q = t >> 1, cc = t & 1;
      cb8[t] = ldin(p.eB1, dir * 1024 + q * 256 + 2 * wl + cc, bfm);
    }
    if (t < 128) cst[t] = 0.f;
  }
  gbar(ctrs, ++genF);                    // full (fenced): y0 from both dirs

  // ============================ E1: 1024 steps =============================
  {
    const int dir = w >> 7, wl = w & 127;
    uint4 pf[8];                         // y0 row-block prefetch (128 B/thread)
    {
      const int tt0 = dir ? 1023 : 0;
      const unsigned short* yr = y0u + (size_t)tt0 * 32768;
#pragma unroll
      for (int i = 0; i < 8; ++i) {
        int u = t + i * THR;
        pf[i] = *reinterpret_cast<const uint4*>(yr + u * 8);
      }
    }
    for (int st = 0; st < 1024; ++st) {
      float4 acc[8];
#pragma unroll
      for (int e = 0; e < 8; ++e) acc[e] = make_float4(0.f, 0.f, 0.f, 0.f);
      const float* hsrc = ws + HBOF + (dir * 2 + (st & 1)) * 16384;
      stage_A_fa(A0, hsrc, 256, 0);
      stage_A_fa(A1, hsrc, 256, 128);
      __syncthreads();
      dot_half(acc, A0, Wl);             // recurrent h part (fp32, K=256)
      dot_half(acc, A1, Wl + 1056);
      __syncthreads();
      // y0 regs -> fp16 LDS tile (64 x 512, stride 520), then prefetch next
#pragma unroll
      for (int i = 0; i < 8; ++i) {
        int u = t + i * THR;
        *reinterpret_cast<uint4*>(Ah + (u >> 6) * AST2 + (u & 63) * 8) = pf[i];
      }
      if (st < 1023) {
        const int tt2 = dir ? (1023 - (st + 1)) : (st + 1);
        const unsigned short* yr = y0u + (size_t)tt2 * 32768;
#pragma unroll
        for (int i = 0; i < 8; ++i) {
          int u = t + i * THR;
          pf[i] = *reinterpret_cast<const uint4*>(yr + u * 8);
        }
      }
      __syncthreads();
      dot2_full(acc, Ah, W16);           // input part (fp16 dot2, K=512)
      reduce_acc(acc, part, gates);
      if (t < 128) {
        const int b = t & 63, cc = t >> 6, c = 2 * wl + cc;
        float gi = gates[(0 + cc) * 64 + b] + cb8[0 + cc];
        float gf = gates[(2 + cc) * 64 + b] + cb8[2 + cc];
        float gg = gates[(4 + cc) * 64 + b] + cb8[4 + cc];
        float go = gates[(6 + cc) * 64 + b] + cb8[6 + cc];
        float cold = cst[cc * 64 + b];
        float cn = sigm(gf) * cold + sigm(gi) * tanhf(gg);
        float hn = sigm(go) * tanhf(cn);
        cst[cc * 64 + b] = cn;
        hstore(&ws[HBOF + (dir * 2 + ((st + 1) & 1)) * 16384 + b * 256 + c], hn);
        if (st == 1023) {
          ws[EHL1 + dir * 16384 + b * 256 + c] = hn;
          ws[ECL1 + dir * 16384 + b * 256 + c] = cn;
        }
      }
      gbarD(ctrs, dir, wl, ++genD);
    }
  }
  gbar(ctrs, ++genF);                    // full: EHL1/ECL1 visible to all dirs

  // ===================== decoder recurrent consts R ========================
  {
    const int m = w >> 6, wl6 = w & 63;
    const void* whh;
    if (bfm) whh = (m < 2) ? (const void*)((const unsigned short*)p.dWhh0 + (size_t)m * 262144)
                           : (const void*)((const unsigned short*)p.dWhh1 + (size_t)(m - 2) * 262144);
    else     whh = (m < 2) ? (const void*)((const float*)p.dWhh0 + (size_t)m * 262144)
                           : (const void*)((const float*)p.dWhh1 + (size_t)(m - 2) * 262144);
    const void* bb;
    if (bfm) bb = (m < 2) ? (const void*)((const unsigned short*)p.dB0 + m * 1024)
                          : (const void*)((const unsigned short*)p.dB1 + (m - 2) * 1024);
    else     bb = (m < 2) ? (const void*)((const float*)p.dB0 + m * 1024)
                          : (const void*)((const float*)p.dB1 + (m - 2) * 1024);
    const unsigned short* asrc_h = nullptr;
    const float* asrc_f = nullptr;
    int astr;
    if (m == 0)      { asrc_h = y0u + (size_t)1023 * 32768; astr = 512; }
    else if (m == 1) { asrc_h = y0u + 256;                  astr = 512; }
    else             { asrc_f = ws + EHL1 + (m - 2) * 16384; astr = 256; }
    float* dst = ws + ROF + m * 65536;
    for (int pass = 0; pass < 2; ++pass) {
      const int rowbase = wl6 * 16 + pass * 8;
      float4 acc[8];
#pragma unroll
      for (int e = 0; e < 8; ++e) acc[e] = make_float4(0.f, 0.f, 0.f, 0.f);
      stage_W_half(Wl,        whh, 256, rowbase, 1, 0,   bfm);
      stage_W_half(Wl + 1056, whh, 256, rowbase, 1, 128, bfm);
      if (asrc_h) { stage_A_h(A0, asrc_h, astr, 0); stage_A_h(A1, asrc_h, astr, 128); }
      else        { stage_A_f(A0, asrc_f, astr, 0); stage_A_f(A1, asrc_f, astr, 128); }
      __syncthreads();
      dot_half(acc, A0, Wl);
      dot_half(acc, A1, Wl + 1056);
      reduce_R(acc, part, dst, bb, rowbase, bfm);
    }
  }
  gbar(ctrs, ++genF);

  // ============================ decoder prep ===============================
  {
    const int dir = w >> 7, wl = w & 127;
    const void* dwih1 = bfm ? (const void*)((const unsigned short*)p.dWih1 + (size_t)dir * 524288)
                            : (const void*)((const float*)p.dWih1 + (size_t)dir * 524288);
#pragma unroll
    for (int qq = 0; qq < 4; ++qq)
      stage_W_half(Wl + (2 + qq) * 1056, dwih1, 512, 2 * wl, 0, qq * 128, bfm);
    if (t < 64) { yprev[t] = 3.0e38f; yprev2[t] = -3.0e38f; }
    dec_z(p, ws, w, 0, nullptr, bfm);     // z_0 from y = 0
  }
  gbar(ctrs, ++genF);

  // ============================ decoder loop ===============================
  {
    const int dir = w >> 7, wl = w & 127;
    float r1i = 0.f, r1f = 0.f, r1g = 0.f, r1o = 0.f, coldc = 0.f, fwc = 0.f;
    if (t < 128) {
      const int b = t & 63, cc = t >> 6, c = 2 * wl + cc;
      const float* rp = ws + ROF + (2 + dir) * 65536 + (size_t)b * 1024;
      r1i = rp[c]; r1f = rp[256 + c]; r1g = rp[512 + c]; r1o = rp[768 + c];
      coldc = ws[ECL1 + dir * 16384 + b * 256 + c];
      fwc = ldin(p.fcW, dir * 256 + c, bfm);
    }
    const float fcb = ldin(p.fcb, 0, bfm);
    int pp = 0;
    for (int st = 0; st < 1024; ++st) {
      // ---- sub-A: l1 gates for our 2 h1-cols, h1, partial y ----
      float4 acc[8];
#pragma unroll
      for (int e = 0; e < 8; ++e) acc[e] = make_float4(0.f, 0.f, 0.f, 0.f);
      const float* zrow = ws + ZBOF + pp * 32768;
      stage_A_f(A0, zrow, 512, 0);
      stage_A_f(A1, zrow, 512, 128);
      __syncthreads();
      dot_half(acc, A0, Wl + 2 * 1056);
      dot_half(acc, A1, Wl + 3 * 1056);
      __syncthreads();
      stage_A_f(A0, zrow, 512, 256);
      stage_A_f(A1, zrow, 512, 384);
      __syncthreads();
      dot_half(acc, A0, Wl + 4 * 1056);
      dot_half(acc, A1, Wl + 5 * 1056);
      reduce_acc(acc, part, gates);
      if (t < 128) {
        const int b = t & 63, cc = t >> 6;
        float gi = gates[(0 + cc) * 64 + b] + r1i;
        float gf = gates[(2 + cc) * 64 + b] + r1f;
        float gg = gates[(4 + cc) * 64 + b] + r1g;
        float go = gates[(6 + cc) * 64 + b] + r1o;
        float cn = sigm(gf) * coldc + sigm(gi) * tanhf(gg);
        float h1 = sigm(go) * tanhf(cn);
        ph[cc * 64 + b] = h1 * fwc;
      }
      __syncthreads();
      if (t < 64) ws[PYOF + w * 64 + t] = ph[t] + ph[64 + t];
      gbar(ctrs, ++genF);

      // ---- sub-B: replicated deterministic y-reduction, output, next z ----
      {
        const int chunk = t >> 6, b = t & 63;
        float s = 0.f;
        for (int j2 = 0; j2 < 32; ++j2) s += ws[PYOF + (chunk * 32 + j2) * 64 + b];
        part[chunk * 64 + b] = s;
        __syncthreads();
        if (t < 64) {
          const float* q = part + t;
          ylds[t] = fcb + (((q[0] + q[64]) + (q[128] + q[192])) +
                           ((q[256] + q[320]) + (q[384] + q[448])));
        }
        __syncthreads();
        int bad1 = (t < 64) ? (ylds[t] != yprev[t] ? 1 : 0) : 0;
        int bad2 = (t < 64) ? (ylds[t] != yprev2[t] ? 1 : 0) : 0;
        int c1 = __syncthreads_count(bad1);
        int c2 = __syncthreads_count(bad2);
        if (t < 64) { yprev2[t] = yprev[t]; yprev[t] = ylds[t]; }
        if (w == 0 && t < 64) stout(p.out, (size_t)t * 1024 + st, ylds[t], bfm);
        if (c1 == 0) {                    // exact fixed point: fill & exit
          if (t < 64) {
            for (int t2 = st + 1 + w; t2 < 1024; t2 += NWG)
              stout(p.out, (size_t)t * 1024 + t2, ylds[t], bfm);
          }
          break;
        }
        if (c2 == 0) {                    // exact period-2 cycle
          if (t < 64) {
            for (int t2 = st + 1 + w; t2 < 1024; t2 += NWG)
              stout(p.out, (size_t)t * 1024 + t2,
                    ((t2 - st) & 1) ? yprev2[t] : ylds[t], bfm);
          }
          break;
        }
        if (st < 1023) {
          __syncthreads();
          dec_z(p, ws, w, pp ^ 1, ylds, bfm);
        }
        gbar(ctrs, ++genF);
        pp ^= 1;
      }
    }
  }
}

// diagnostic: if ws too small, encode ws_size (MB) into the output signature
__global__ void fill_sig(unsigned short* out, int n, float val) {
  int i = blockIdx.x * 256 + threadIdx.x;
  __hip_bfloat16 b = __float2bfloat16(val);
  if (i < n) out[i] = *reinterpret_cast<unsigned short*>(&b);
}

extern "C" void kernel_launch(void* const* d_in, const int* in_sizes, int n_in,
                              void* d_out, int out_size, void* d_ws, size_t ws_size,
                              hipStream_t stream) {
  (void)in_sizes; (void)n_in;
  if (ws_size < WS_REQ_BYTES) {
    float sig = 2048.0f + (float)(ws_size >> 20);
    fill_sig<<<(out_size + 255) / 256, 256, 0, stream>>>(
        (unsigned short*)d_out, out_size, sig);
    return;
  }
  hipMemsetAsync(d_ws, 0, 8192, stream);  // zero barrier counters (full + dir)

  SeqParams p;
  p.x     = d_in[0];
  p.eWih0 = d_in[1];
  p.eWhh0 = d_in[2];
  p.eB0   = d_in[3];
  p.eWih1 = d_in[4];
  p.eWhh1 = d_in[5];
  p.eB1   = d_in[6];
  p.dWih0 = d_in[7];
  p.dWhh0 = d_in[8];
  p.dB0   = d_in[9];
  p.dWih1 = d_in[10];
  p.dWhh1 = d_in[11];
  p.dB1   = d_in[12];
  p.fcW   = d_in[13];
  p.fcb   = d_in[14];
  p.out   = d_out;
  p.ws    = (float*)d_ws;
  p.ctrs  = (unsigned*)d_ws;

  seq2seq_kernel<<<dim3(NWG), dim3(THR), 0, stream>>>(p);
}

// Round 2
// 15977.055 us; speedup vs baseline: 2.1573x; 1.2820x over previous
//
#include <hip/hip_runtime.h>
#include <hip/hip_bf16.h>
#include <hip/hip_fp16.h>
#include <math.h>

// ---------------------------------------------------------------------------
// Seq2Seq (bi-LSTM encoder x2 layers + fixed-state decoder), B=64 T=1024 H=256
// This round:
//  * h exchanged as PACKED fp16 pairs via agent-scope relaxed (sc1) 4B stores;
//    c-state stays fp32 in registers. All LDS tiles fp16, all dots via
//    v_dot2_f32_f16 (fp32 accumulate).
//  * ALL weights (Whh/Wih/dWih1/dWhh) live in VGPRs as packed fp16 -> zero
//    weight LDS traffic; LDS down to ~120 KB.
//  * E1 dir-barrier split arrive/wait: the K=512 y0-dot (h-independent) runs
//    between arrive and wait, hiding barrier propagation.
//  * E0/E1 last-step h-store guarded off (dead) so phase-prep zeroing cannot
//    race the write-through stores.
// ---------------------------------------------------------------------------

#define NWG 256
#define THR 512
#define U0S 132      // AH0 stride in uints (64 x 128-uint h tile, K=256 halves)
#define U1S 260      // AH1 stride in uints (64 x 256-uint tile,  K=512 halves)

// ws layout (float offsets); first 2048 floats = barrier counters (8 KB)
#define HBOF   2048                 // packed fp16 h dbuf: uint[(dir*2+buf)*8192 + b*128 + wl]
#define ECL0   (HBOF + 65536)       // enc l0 final c (fp32): [dir*16384 + b*256 + k]
#define EHL1   (ECL0 + 32768)       // enc l1 final h (packed fp16): uint[dir*8192 + b*128 + wl]
#define ECL1   (EHL1 + 32768)       // enc l1 final c (fp32)
#define ROF    (ECL1 + 32768)       // decoder recurrent consts R (fp32): [m*65536 + b*1024 + r]
#define ZBOF   (ROF + 262144)       // decoder z dbuf (fp16): ushort[sel*32768 + b*512 + j]
#define PYOF   (ZBOF + 65536)       // decoder partial y (fp32): [w*64+b]
#define Y0OF   524288               // packed fp16 y0: uint[t*16384 + b*256 + dir*128 + wl]
#define WS_REQ_BYTES ((size_t)(Y0OF + 16777216) * 4)   // ~66 MB (unchanged)

struct SeqParams {
  const void *x, *eWih0, *eWhh0, *eB0, *eWih1, *eWhh1, *eB1;
  const void *dWih0, *dWhh0, *dB0, *dWih1, *dWhh1, *dB1, *fcW, *fcb;
  void* out;
  float* ws;
  unsigned* ctrs;
};

typedef _Float16 hlf2 __attribute__((ext_vector_type(2)));

__device__ __forceinline__ float bf2f(unsigned short u) {
  return __uint_as_float(((unsigned)u) << 16);
}
__device__ __forceinline__ unsigned short f2h_u(float f) {
  __half h = __float2half(f);
  return *reinterpret_cast<unsigned short*>(&h);
}
__device__ __forceinline__ float sigm(float v) { return 1.0f / (1.0f + expf(-v)); }

#if __has_builtin(__builtin_amdgcn_fdot2)
__device__ __forceinline__ float fdot2(hlf2 a, hlf2 b, float c) {
  return __builtin_amdgcn_fdot2(a, b, c, false);
}
#else
__device__ __forceinline__ float fdot2(hlf2 a, hlf2 b, float c) {
  return c + (float)a[0] * (float)b[0] + (float)a[1] * (float)b[1];
}
#endif

__device__ __forceinline__ float ldin(const void* p_, size_t i, int bf) {
  return bf ? bf2f(((const unsigned short*)p_)[i]) : ((const float*)p_)[i];
}
__device__ __forceinline__ void stout(void* o, size_t i, float v, int bf) {
  if (bf) ((__hip_bfloat16*)o)[i] = __float2bfloat16(v);
  else    ((float*)o)[i] = v;
}

// probe storage dtype from x (N(0,1) samples)
__device__ __forceinline__ int detect_bf16(const void* xp) {
  const unsigned* u = (const unsigned*)xp;
  int votes = 0;
#pragma unroll 8
  for (int i = 0; i < 64; ++i) {
    unsigned e = (u[i] >> 7) & 0xFF;
    votes += (e >= 108 && e <= 131) ? 1 : 0;
  }
  return votes >= 32;
}

// ---- coherent-point (sc1) packed-h exchange --------------------------------
__device__ __forceinline__ uint4 hload4u(const unsigned* p2) {
  unsigned long long u0 = __hip_atomic_load((const unsigned long long*)p2,
                                            __ATOMIC_RELAXED, __HIP_MEMORY_SCOPE_AGENT);
  unsigned long long u1 = __hip_atomic_load((const unsigned long long*)p2 + 1,
                                            __ATOMIC_RELAXED, __HIP_MEMORY_SCOPE_AGENT);
  return make_uint4((unsigned)u0, (unsigned)(u0 >> 32),
                    (unsigned)u1, (unsigned)(u1 >> 32));
}

// ---- full barrier (fenced release/acquire; phase transitions) --------------
__device__ __forceinline__ void gbar(unsigned* ctrs, unsigned gen) {
  __syncthreads();
  if (threadIdx.x == 0) {
    __hip_atomic_fetch_add(&ctrs[(blockIdx.x & 31) * 32], 1u,
                           __ATOMIC_RELEASE, __HIP_MEMORY_SCOPE_AGENT);
  }
  if (threadIdx.x < 32) {
    while (__hip_atomic_load(&ctrs[threadIdx.x * 32], __ATOMIC_RELAXED,
                             __HIP_MEMORY_SCOPE_AGENT) < gen * 8u) {
      __builtin_amdgcn_s_sleep(1);
    }
    (void)__hip_atomic_load(&ctrs[threadIdx.x * 32], __ATOMIC_ACQUIRE,
                            __HIP_MEMORY_SCOPE_AGENT);
  }
  __syncthreads();
}

// ---- per-direction split barrier (fence-free; h moves via sc1 atomics) -----
// arriveD: __syncthreads drains vmcnt -> sc1 stores at coherent point before
// the relaxed add. waitD: relaxed spin + compiler-only acquire fence.
__device__ __forceinline__ void arriveD(unsigned* ctrs, int grp) {
  __syncthreads();
  if (threadIdx.x == 0) {
    __hip_atomic_fetch_add(&ctrs[(32 + grp) * 32], 1u,
                           __ATOMIC_RELAXED, __HIP_MEMORY_SCOPE_AGENT);
  }
}
__device__ __forceinline__ void waitD(unsigned* ctrs, int dir, unsigned target) {
  if (threadIdx.x < 16) {
    while (__hip_atomic_load(&ctrs[(32 + dir * 16 + (int)threadIdx.x) * 32],
                             __ATOMIC_RELAXED, __HIP_MEMORY_SCOPE_AGENT) < target) {
      __builtin_amdgcn_s_sleep(1);
    }
  }
  __atomic_signal_fence(__ATOMIC_ACQUIRE);
  __syncthreads();
}

// ---- staging ---------------------------------------------------------------
// packed-h 64x128-uint tile via sc1 loads -> AH0 (stride U0S)
__device__ __forceinline__ void stage_h16(unsigned* AH, const unsigned* src) {
  const int t = threadIdx.x;
#pragma unroll
  for (int i = 0; i < 4; ++i) {
    int idx = t + i * THR;
    int r = idx >> 5, c4 = (idx & 31) << 2;
    uint4 v = hload4u(src + r * 128 + c4);
    *reinterpret_cast<uint4*>(AH + r * U0S + c4) = v;
  }
}
// plain 64x128-uint tile (K=256 halves) from arbitrary uint stride/offset
__device__ __forceinline__ void stage_u128(unsigned* AH, const unsigned* src,
                                           int ustr, int uoff) {
  const int t = threadIdx.x;
#pragma unroll
  for (int i = 0; i < 4; ++i) {
    int idx = t + i * THR;
    int r = idx >> 5, c4 = (idx & 31) << 2;
    uint4 v = *reinterpret_cast<const uint4*>(src + (size_t)r * ustr + uoff + c4);
    *reinterpret_cast<uint4*>(AH + r * U0S + c4) = v;
  }
}
// plain 64x256-uint tile (K=512 halves), global stride 256 -> AH1
__device__ __forceinline__ void stage_u256(unsigned* AH, const unsigned* src) {
  const int t = threadIdx.x;
#pragma unroll
  for (int i = 0; i < 8; ++i) {
    int idx = t + i * THR;
    int r = idx >> 6, c4 = (idx & 63) << 2;
    uint4 v = *reinterpret_cast<const uint4*>(src + (size_t)r * 256 + c4);
    *reinterpret_cast<uint4*>(AH + r * U1S + c4) = v;
  }
}

// ---- weight-register loads (one-time per phase) ----------------------------
// 8-half chunk of a weight row (bf16 or fp32 global) -> packed fp16 uint4
__device__ __forceinline__ uint4 ldw8(const void* src, size_t off, int bf) {
  union { __half h[8]; uint4 u; } r;
  if (bf) {
    const unsigned short* s = (const unsigned short*)src + off;
    ushort4 a = *reinterpret_cast<const ushort4*>(s);
    ushort4 b = *reinterpret_cast<const ushort4*>(s + 4);
    r.h[0] = __float2half(bf2f(a.x)); r.h[1] = __float2half(bf2f(a.y));
    r.h[2] = __float2half(bf2f(a.z)); r.h[3] = __float2half(bf2f(a.w));
    r.h[4] = __float2half(bf2f(b.x)); r.h[5] = __float2half(bf2f(b.y));
    r.h[6] = __float2half(bf2f(b.z)); r.h[7] = __float2half(bf2f(b.w));
  } else {
    const float* s = (const float*)src + off;
    float4 a = *reinterpret_cast<const float4*>(s);
    float4 b = *reinterpret_cast<const float4*>(s + 4);
    r.h[0] = __float2half(a.x); r.h[1] = __float2half(a.y);
    r.h[2] = __float2half(a.z); r.h[3] = __float2half(a.w);
    r.h[4] = __float2half(b.x); r.h[5] = __float2half(b.y);
    r.h[6] = __float2half(b.z); r.h[7] = __float2half(b.w);
  }
  return r.u;
}
// gate-major col-pair rows: grow = rt*256 + colbase + j ; KH halves per row
template<int ND>
__device__ __forceinline__ void load_w16(uint4 (&wr)[2][ND], const void* src,
                                         int KH, int colbase, int bf) {
  const int t = threadIdx.x, kc = t >> 6, rt = t & 3;
#pragma unroll
  for (int j = 0; j < 2; ++j) {
    size_t rb = (size_t)(rt * 256 + colbase + j) * KH + kc * (ND * 8);
#pragma unroll
    for (int d = 0; d < ND; ++d) wr[j][d] = ldw8(src, rb + d * 8, bf);
  }
}
// consecutive rows: grow = rowbase + rt*2 + j (K=256; R phase)
__device__ __forceinline__ void load_w16_rows(uint4 (&wr)[2][4], const void* src,
                                              int rowbase, int bf) {
  const int t = threadIdx.x, kc = t >> 6, rt = t & 3;
#pragma unroll
  for (int j = 0; j < 2; ++j) {
    size_t rb = (size_t)(rowbase + rt * 2 + j) * 256 + kc * 32;
#pragma unroll
    for (int d = 0; d < 4; ++d) wr[j][d] = ldw8(src, rb + d * 8, bf);
  }
}

// ---- fp16 dot (v_dot2_f32_f16, fp32 accum), W from registers ---------------
__device__ __forceinline__ void dot2acc(float4& a, const uint4& hv, const uint4& wv) {
  const hlf2* hp = reinterpret_cast<const hlf2*>(&hv);
  const hlf2* wp = reinterpret_cast<const hlf2*>(&wv);
  a.x = fdot2(hp[0], wp[0], a.x);
  a.y = fdot2(hp[1], wp[1], a.y);
  a.z = fdot2(hp[2], wp[2], a.z);
  a.w = fdot2(hp[3], wp[3], a.w);
}
// acc[i*2+j] += A[bt+16i][k] * W[j][k]; kc = wave (uniform K-chunk) ->
// <=16 distinct LDS rows per instr, 4-lane broadcast, 2-way max (free).
template<int ND, int USTR>
__device__ __forceinline__ void dot2_t(float4* acc, const unsigned* A,
                                       const uint4 (&wr)[2][ND]) {
  const int t = threadIdx.x;
  const int kc = t >> 6, bt = (t & 63) >> 2;
#pragma unroll
  for (int d = 0; d < ND; ++d) {
    const int k = kc * (ND * 4) + d * 4;
    uint4 h0 = *reinterpret_cast<const uint4*>(A + (bt +  0) * USTR + k);
    uint4 h1 = *reinterpret_cast<const uint4*>(A + (bt + 16) * USTR + k);
    uint4 h2 = *reinterpret_cast<const uint4*>(A + (bt + 32) * USTR + k);
    uint4 h3 = *reinterpret_cast<const uint4*>(A + (bt + 48) * USTR + k);
    dot2acc(acc[0], h0, wr[0][d]); dot2acc(acc[1], h0, wr[1][d]);
    dot2acc(acc[2], h1, wr[0][d]); dot2acc(acc[3], h1, wr[1][d]);
    dot2acc(acc[4], h2, wr[0][d]); dot2acc(acc[5], h2, wr[1][d]);
    dot2acc(acc[6], h3, wr[0][d]); dot2acc(acc[7], h3, wr[1][d]);
  }
}

// deterministic 8-partial reduction -> gates[r*64+b] (8x64)
__device__ __forceinline__ void reduce_acc(const float4* acc, float* part, float* outbuf) {
  const int t = threadIdx.x;
  const int kc = t >> 6, tile = t & 63;
#pragma unroll
  for (int e = 0; e < 8; ++e) {
    const float4 a = acc[e];
    part[e * 512 + kc * 64 + tile] = (a.x + a.y) + (a.z + a.w);
  }
  __syncthreads();
  {
    const int r = t >> 6, b = t & 63;
    const int tl = (b & 15) * 4 + (r >> 1);
    const float* pp = part + ((b >> 4) * 2 + (r & 1)) * 512 + tl;
    float v = ((pp[0] + pp[64]) + (pp[128] + pp[192])) +
              ((pp[256] + pp[320]) + (pp[384] + pp[448]));
    outbuf[r * 64 + b] = v;
  }
  __syncthreads();
}

// same reduction but writes R consts to global with bias added
__device__ __forceinline__ void reduce_R(const float4* acc, float* part, float* dst,
                                         const void* bsrc, int rowbase, int bf) {
  const int t = threadIdx.x;
  const int kc = t >> 6, tile = t & 63;
#pragma unroll
  for (int e = 0; e < 8; ++e) {
    const float4 a = acc[e];
    part[e * 512 + kc * 64 + tile] = (a.x + a.y) + (a.z + a.w);
  }
  __syncthreads();
  {
    const int r = t >> 6, b = t & 63;
    const int tl = (b & 15) * 4 + (r >> 1);
    const float* pp = part + ((b >> 4) * 2 + (r & 1)) * 512 + tl;
    float v = ((pp[0] + pp[64]) + (pp[128] + pp[192])) +
              ((pp[256] + pp[320]) + (pp[384] + pp[448]));
    dst[(size_t)b * 1024 + rowbase + r] = v + ldin(bsrc, rowbase + r, bf);
  }
  __syncthreads();
}

// decoder layer-0 cells: z[b][j] (fp16) from scalar y (WG w owns 128 elements)
__device__ __forceinline__ void dec_z(const SeqParams& p, float* ws, int w, int bufsel,
                                      const float* yl, int bf) {
  const int t = threadIdx.x;
  if (t < 128) {
    int e = w * 128 + t;
    int b = e >> 9, j = e & 511;
    int dir = j >> 8, k = j & 255;
    float y = yl ? yl[b] : 0.f;
    const float* rp = ws + ROF + dir * 65536 + (size_t)b * 1024;
    float gi = y * ldin(p.dWih0, dir * 1024 +       k, bf) + rp[      k];
    float gf = y * ldin(p.dWih0, dir * 1024 + 256 + k, bf) + rp[256 + k];
    float gg = y * ldin(p.dWih0, dir * 1024 + 512 + k, bf) + rp[512 + k];
    float go = y * ldin(p.dWih0, dir * 1024 + 768 + k, bf) + rp[768 + k];
    float cold = ws[ECL0 + dir * 16384 + b * 256 + k];
    float cn = sigm(gf) * cold + sigm(gi) * tanhf(gg);
    float hz = sigm(go) * tanhf(cn);
    ((unsigned short*)(ws + ZBOF))[bufsel * 32768 + b * 512 + j] = f2h_u(hz);
  }
}

__global__ void __launch_bounds__(THR, 1) seq2seq_kernel(SeqParams p) {
  __shared__ __align__(16) unsigned AH0[64 * U0S];   // 33792 B fp16 h tile
  __shared__ __align__(16) unsigned AH1[64 * U1S];   // 66560 B fp16 K=512 tile
  __shared__ __align__(16) float part[8 * 512];      // 16384 B
  __shared__ float gates[8 * 64];
  __shared__ float ph[2 * 64];
  __shared__ float cb8[8], cw8[8];
  __shared__ float ylds[64], yprev[64], yprev2[64];

  const int w = blockIdx.x;
  const int t = threadIdx.x;
  float* ws = p.ws;
  unsigned* H16u  = (unsigned*)(ws + HBOF);
  unsigned* EHL1u = (unsigned*)(ws + EHL1);
  unsigned* y0w   = (unsigned*)(ws + Y0OF);
  unsigned* ctrs = p.ctrs;
  unsigned genF = 0, dtgt = 0;
  const int bfm = detect_bf16(p.x);
  const int dir = w >> 7, wl = w & 127;
  const int grp = dir * 16 + (wl >> 3);

  uint4 wrA[2][4];    // K=256 weight regs (E0 Whh / E1 Whh / R dWhh)
  uint4 wrB[2][8];    // K=512 weight regs (E1 Wih / decoder dWih1)

  // ============================ init + E0 prep =============================
  {
    if (t < 64) {                       // zero packed-h buf0, both dirs
      int e = w * 64 + t;
      int dz = e >> 13, r = e & 8191;
      H16u[(dz * 2) * 8192 + r] = 0u;
    }
    const void* whh0 = bfm ? (const void*)((const unsigned short*)p.eWhh0 + (size_t)dir * 262144)
                           : (const void*)((const float*)p.eWhh0 + (size_t)dir * 262144);
    load_w16<4>(wrA, whh0, 256, 2 * wl, bfm);
    if (t < 8) {
      int q = t >> 1, cc = t & 1;
      int grow = q * 256 + 2 * wl + cc;
      cb8[t] = ldin(p.eB0,   dir * 1024 + grow, bfm);
      cw8[t] = ldin(p.eWih0, dir * 1024 + grow, bfm);
    }
  }
  gbar(ctrs, ++genF);                    // fenced: zeros visible everywhere

  // ============================ E0: 1024 steps =============================
  {
    float c0 = 0.f, c1 = 0.f;
    for (int st = 0; st < 1024; ++st) {
      const int tt = dir ? (1023 - st) : st;
      float xv = 0.f;
      if (t < 64) xv = ldin(p.x, (size_t)t * 1024 + tt, bfm);
      waitD(ctrs, dir, dtgt * 8u);       // h[st] at coherent point
      stage_h16(AH0, H16u + (dir * 2 + (st & 1)) * 8192);
      __syncthreads();
      float4 acc[8];
#pragma unroll
      for (int e = 0; e < 8; ++e) acc[e] = make_float4(0.f, 0.f, 0.f, 0.f);
      dot2_t<4, U0S>(acc, AH0, wrA);
      reduce_acc(acc, part, gates);
      if (t < 64) {
        const int b = t;
        float hh[2];
#pragma unroll
        for (int cc = 0; cc < 2; ++cc) {
          float gi = gates[(0 + cc) * 64 + b] + cb8[0 + cc] + xv * cw8[0 + cc];
          float gf = gates[(2 + cc) * 64 + b] + cb8[2 + cc] + xv * cw8[2 + cc];
          float gg = gates[(4 + cc) * 64 + b] + cb8[4 + cc] + xv * cw8[4 + cc];
          float go = gates[(6 + cc) * 64 + b] + cb8[6 + cc] + xv * cw8[6 + cc];
          float cold = cc ? c1 : c0;
          float cn = sigm(gf) * cold + sigm(gi) * tanhf(gg);
          float hn = sigm(go) * tanhf(cn);
          if (cc) c1 = cn; else c0 = cn;
          hh[cc] = hn;
        }
        unsigned pw = (unsigned)f2h_u(hh[0]) | ((unsigned)f2h_u(hh[1]) << 16);
        if (st < 1023)
          __hip_atomic_store(&H16u[(dir * 2 + ((st + 1) & 1)) * 8192 + b * 128 + wl],
                             pw, __ATOMIC_RELAXED, __HIP_MEMORY_SCOPE_AGENT);
        y0w[(size_t)tt * 16384 + b * 256 + dir * 128 + wl] = pw;  // plain; phase-fenced
        if (st == 1023) {
          ws[ECL0 + dir * 16384 + b * 256 + 2 * wl]     = c0;
          ws[ECL0 + dir * 16384 + b * 256 + 2 * wl + 1] = c1;
        }
      }
      arriveD(ctrs, grp); ++dtgt;
    }
  }

  // ============================ E1 prep ====================================
  {
    if (t < 64) {                       // re-zero packed-h buf0 (safe: no
      int e = w * 64 + t;               // writer touches buf0 after step 1022)
      int dz = e >> 13, r = e & 8191;
      H16u[(dz * 2) * 8192 + r] = 0u;
    }
    const void* whh1 = bfm ? (const void*)((const unsigned short*)p.eWhh1 + (size_t)dir * 262144)
                           : (const void*)((const float*)p.eWhh1 + (size_t)dir * 262144);
    const void* wih1 = bfm ? (const void*)((const unsigned short*)p.eWih1 + (size_t)dir * 524288)
                           : (const void*)((const float*)p.eWih1 + (size_t)dir * 524288);
    load_w16<4>(wrA, whh1, 256, 2 * wl, bfm);
    load_w16<8>(wrB, wih1, 512, 2 * wl, bfm);
    if (t < 8) {
      int q = t >> 1, cc = t & 1;
      cb8[t] = ldin(p.eB1, dir * 1024 + q * 256 + 2 * wl + cc, bfm);
    }
  }
  gbar(ctrs, ++genF);                    // fenced: y0 + zeros visible

  // ============================ E1: 1024 steps =============================
  {
    float c0 = 0.f, c1 = 0.f;
    uint4 pf[8];                         // y0 row prefetch (128 B/thread)
    {
      const int tt0 = dir ? 1023 : 0;
      const unsigned* yr = y0w + (size_t)tt0 * 16384;
#pragma unroll
      for (int i = 0; i < 8; ++i)
        pf[i] = *reinterpret_cast<const uint4*>(yr + (t + i * THR) * 4);
    }
    for (int st = 0; st < 1024; ++st) {
      // ---- h-independent work first: y0 tile + K=512 dot (hides barrier) --
#pragma unroll
      for (int i = 0; i < 8; ++i) {
        int u = t + i * THR;
        *reinterpret_cast<uint4*>(AH1 + (u >> 6) * U1S + (u & 63) * 4) = pf[i];
      }
      if (st < 1023) {
        const int tt2 = dir ? (1022 - st) : (st + 1);
        const unsigned* yr = y0w + (size_t)tt2 * 16384;
#pragma unroll
        for (int i = 0; i < 8; ++i)
          pf[i] = *reinterpret_cast<const uint4*>(yr + (t + i * THR) * 4);
      }
      __syncthreads();
      float4 acc[8];
#pragma unroll
      for (int e = 0; e < 8; ++e) acc[e] = make_float4(0.f, 0.f, 0.f, 0.f);
      dot2_t<8, U1S>(acc, AH1, wrB);     // input part (K=512)
      // ---- now the recurrent part ----
      waitD(ctrs, dir, dtgt * 8u);
      stage_h16(AH0, H16u + (dir * 2 + (st & 1)) * 8192);
      __syncthreads();
      dot2_t<4, U0S>(acc, AH0, wrA);     // recurrent part (K=256)
      reduce_acc(acc, part, gates);
      if (t < 64) {
        const int b = t;
        float hh[2];
#pragma unroll
        for (int cc = 0; cc < 2; ++cc) {
          float gi = gates[(0 + cc) * 64 + b] + cb8[0 + cc];
          float gf = gates[(2 + cc) * 64 + b] + cb8[2 + cc];
          float gg = gates[(4 + cc) * 64 + b] + cb8[4 + cc];
          float go = gates[(6 + cc) * 64 + b] + cb8[6 + cc];
          float cold = cc ? c1 : c0;
          float cn = sigm(gf) * cold + sigm(gi) * tanhf(gg);
          float hn = sigm(go) * tanhf(cn);
          if (cc) c1 = cn; else c0 = cn;
          hh[cc] = hn;
        }
        unsigned pw = (unsigned)f2h_u(hh[0]) | ((unsigned)f2h_u(hh[1]) << 16);
        if (st < 1023)
          __hip_atomic_store(&H16u[(dir * 2 + ((st + 1) & 1)) * 8192 + b * 128 + wl],
                             pw, __ATOMIC_RELAXED, __HIP_MEMORY_SCOPE_AGENT);
        if (st == 1023) {
          EHL1u[dir * 8192 + b * 128 + wl] = pw;   // plain; phase-fenced
          ws[ECL1 + dir * 16384 + b * 256 + 2 * wl]     = c0;
          ws[ECL1 + dir * 16384 + b * 256 + 2 * wl + 1] = c1;
        }
      }
      arriveD(ctrs, grp); ++dtgt;
    }
  }
  gbar(ctrs, ++genF);                    // fenced: EHL1/ECL1 visible

  // ===================== decoder recurrent consts R ========================
  {
    const int m = w >> 6, wl6 = w & 63;
    const void* whh;
    if (bfm) whh = (m < 2) ? (const void*)((const unsigned short*)p.dWhh0 + (size_t)m * 262144)
                           : (const void*)((const unsigned short*)p.dWhh1 + (size_t)(m - 2) * 262144);
    else     whh = (m < 2) ? (const void*)((const float*)p.dWhh0 + (size_t)m * 262144)
                           : (const void*)((const float*)p.dWhh1 + (size_t)(m - 2) * 262144);
    const void* bb;
    if (bfm) bb = (m < 2) ? (const void*)((const unsigned short*)p.dB0 + m * 1024)
                          : (const void*)((const unsigned short*)p.dB1 + (m - 2) * 1024);
    else     bb = (m < 2) ? (const void*)((const float*)p.dB0 + m * 1024)
                          : (const void*)((const float*)p.dB1 + (m - 2) * 1024);
    // A sources (all K=256, fp16): m0=hf0 (y0[1023] fwd half), m1=hb0
    // (y0[0] bwd half), m2/3 = EHL1
    if (m == 0)      stage_u128(AH0, y0w + (size_t)1023 * 16384, 256, 0);
    else if (m == 1) stage_u128(AH0, y0w, 256, 128);
    else             stage_u128(AH0, EHL1u + (m - 2) * 8192, 128, 0);
    __syncthreads();
    float* dst = ws + ROF + m * 65536;
    for (int pass = 0; pass < 2; ++pass) {
      const int rowbase = wl6 * 16 + pass * 8;
      load_w16_rows(wrA, whh, rowbase, bfm);
      float4 acc[8];
#pragma unroll
      for (int e = 0; e < 8; ++e) acc[e] = make_float4(0.f, 0.f, 0.f, 0.f);
      dot2_t<4, U0S>(acc, AH0, wrA);
      reduce_R(acc, part, dst, bb, rowbase, bfm);
    }
  }
  gbar(ctrs, ++genF);

  // ============================ decoder prep ===============================
  {
    const void* dwih1 = bfm ? (const void*)((const unsigned short*)p.dWih1 + (size_t)dir * 524288)
                            : (const void*)((const float*)p.dWih1 + (size_t)dir * 524288);
    load_w16<8>(wrB, dwih1, 512, 2 * wl, bfm);
    if (t < 64) { yprev[t] = 3.0e38f; yprev2[t] = -3.0e38f; }
    dec_z(p, ws, w, 0, nullptr, bfm);     // z_0 from y = 0
  }
  gbar(ctrs, ++genF);

  // ============================ decoder loop ===============================
  {
    float r1i = 0.f, r1f = 0.f, r1g = 0.f, r1o = 0.f, coldc = 0.f, fwc = 0.f;
    if (t < 128) {
      const int b = t & 63, cc = t >> 6, c = 2 * wl + cc;
      const float* rp = ws + ROF + (2 + dir) * 65536 + (size_t)b * 1024;
      r1i = rp[c]; r1f = rp[256 + c]; r1g = rp[512 + c]; r1o = rp[768 + c];
      coldc = ws[ECL1 + dir * 16384 + b * 256 + c];
      fwc = ldin(p.fcW, dir * 256 + c, bfm);
    }
    const float fcb = ldin(p.fcb, 0, bfm);
    int pp = 0;
    for (int st = 0; st < 1024; ++st) {
      // ---- sub-A: l1 gates for our 2 h1-cols, h1, partial y ----
      stage_u256(AH1, (const unsigned*)(ws + ZBOF) + pp * 16384);
      __syncthreads();
      float4 acc[8];
#pragma unroll
      for (int e = 0; e < 8; ++e) acc[e] = make_float4(0.f, 0.f, 0.f, 0.f);
      dot2_t<8, U1S>(acc, AH1, wrB);
      reduce_acc(acc, part, gates);
      if (t < 128) {
        const int b = t & 63, cc = t >> 6;
        float gi = gates[(0 + cc) * 64 + b] + r1i;
        float gf = gates[(2 + cc) * 64 + b] + r1f;
        float gg = gates[(4 + cc) * 64 + b] + r1g;
        float go = gates[(6 + cc) * 64 + b] + r1o;
        float cn = sigm(gf) * coldc + sigm(gi) * tanhf(gg);
        float h1 = sigm(go) * tanhf(cn);
        ph[cc * 64 + b] = h1 * fwc;
      }
      __syncthreads();
      if (t < 64) ws[PYOF + w * 64 + t] = ph[t] + ph[64 + t];
      gbar(ctrs, ++genF);

      // ---- sub-B: replicated deterministic y-reduction, output, next z ----
      {
        const int chunk = t >> 6, b = t & 63;
        float s = 0.f;
        for (int j2 = 0; j2 < 32; ++j2) s += ws[PYOF + (chunk * 32 + j2) * 64 + b];
        part[chunk * 64 + b] = s;
        __syncthreads();
        if (t < 64) {
          const float* q = part + t;
          ylds[t] = fcb + (((q[0] + q[64]) + (q[128] + q[192])) +
                           ((q[256] + q[320]) + (q[384] + q[448])));
        }
        __syncthreads();
        int bad1 = (t < 64) ? (ylds[t] != yprev[t] ? 1 : 0) : 0;
        int bad2 = (t < 64) ? (ylds[t] != yprev2[t] ? 1 : 0) : 0;
        int c1n = __syncthreads_count(bad1);
        int c2n = __syncthreads_count(bad2);
        if (t < 64) { yprev2[t] = yprev[t]; yprev[t] = ylds[t]; }
        if (w == 0 && t < 64) stout(p.out, (size_t)t * 1024 + st, ylds[t], bfm);
        if (c1n == 0) {                   // exact fixed point: fill & exit
          if (t < 64) {
            for (int t2 = st + 1 + w; t2 < 1024; t2 += NWG)
              stout(p.out, (size_t)t * 1024 + t2, ylds[t], bfm);
          }
          break;
        }
        if (c2n == 0) {                   // exact period-2 cycle
          if (t < 64) {
            for (int t2 = st + 1 + w; t2 < 1024; t2 += NWG)
              stout(p.out, (size_t)t * 1024 + t2,
                    ((t2 - st) & 1) ? yprev2[t] : ylds[t], bfm);
          }
          break;
        }
        if (st < 1023) {
          __syncthreads();
          dec_z(p, ws, w, pp ^ 1, ylds, bfm);
        }
        gbar(ctrs, ++genF);
        pp ^= 1;
      }
    }
  }
}

// diagnostic: if ws too small, encode ws_size (MB) into the output signature
__global__ void fill_sig(unsigned short* out, int n, float val) {
  int i = blockIdx.x * 256 + threadIdx.x;
  __hip_bfloat16 b = __float2bfloat16(val);
  if (i < n) out[i] = *reinterpret_cast<unsigned short*>(&b);
}

extern "C" void kernel_launch(void* const* d_in, const int* in_sizes, int n_in,
                              void* d_out, int out_size, void* d_ws, size_t ws_size,
                              hipStream_t stream) {
  (void)in_sizes; (void)n_in;
  if (ws_size < WS_REQ_BYTES) {
    float sig = 2048.0f + (float)(ws_size >> 20);
    fill_sig<<<(out_size + 255) / 256, 256, 0, stream>>>(
        (unsigned short*)d_out, out_size, sig);
    return;
  }
  hipMemsetAsync(d_ws, 0, 8192, stream);  // zero barrier counters (full + dir)

  SeqParams p;
  p.x     = d_in[0];
  p.eWih0 = d_in[1];
  p.eWhh0 = d_in[2];
  p.eB0   = d_in[3];
  p.eWih1 = d_in[4];
  p.eWhh1 = d_in[5];
  p.eB1   = d_in[6];
  p.dWih0 = d_in[7];
  p.dWhh0 = d_in[8];
  p.dB0   = d_in[9];
  p.dWih1 = d_in[10];
  p.dWhh1 = d_in[11];
  p.dB1   = d_in[12];
  p.fcW   = d_in[13];
  p.fcb   = d_in[14];
  p.out   = d_out;
  p.ws    = (float*)d_ws;
  p.ctrs  = (unsigned*)d_ws;

  seq2seq_kernel<<<dim3(NWG), dim3(THR), 0, stream>>>(p);
}